// Round 8
// baseline (233.140 us; speedup 1.0000x reference)
//
#include <hip/hip_runtime.h>
#include <hip/hip_bf16.h>
#include <math.h>

#define N_TOK 8192
#define DIM 1024
#define NEXP 16
#define CAP 1280
#define FDIM 512
#define NROUTE (N_TOK * 2)
#define NCHUNK 64
#define ECAP (NEXP * CAP)        /* 20480 */
#define TOTROW (ECAP + N_TOK)    /* 28672 */

typedef __hip_bfloat16 bf16;
typedef unsigned short ushort_t;
typedef __attribute__((ext_vector_type(8))) short bf16x8;
typedef __attribute__((ext_vector_type(4))) float f32x4;

// tanh-approx gelu via sigmoid: gelu(x) ~= x * sigmoid(2c(x + 0.044715 x^3)).
// max abs error vs exact erf-gelu ~1e-3 << bf16 tolerance.
__device__ __forceinline__ float gelu_fast(float x) {
    float u = 1.5957691216057308f * (x + 0.044715f * x * x * x);
    return x / (1.f + __expf(-u));
}

__device__ __forceinline__ float bf2f(unsigned short u) {
    union { float f; unsigned int i; } v; v.i = ((unsigned int)u) << 16; return v.f;
}

__device__ __forceinline__ unsigned short f2b(float f) {
    union { __hip_bfloat16 h; unsigned short u; } v;
    v.h = __float2bfloat16(f);
    return v.u;
}

__device__ __forceinline__ void gload16(const void* g, void* l) {
    __builtin_amdgcn_global_load_lds(
        (const __attribute__((address_space(1))) unsigned int*)g,
        (__attribute__((address_space(3))) unsigned int*)l,
        16, 0, 0);
}

// T2 both-sides swizzle (verified: SQ_LDS_BANK_CONFLICT -> 0, rounds 5-7)
__device__ __forceinline__ int swz_addr16(int r, int q) {
    return ((r >> 1) << 3) + ((r & 1) << 2) + (q ^ ((r >> 1) & 3));
}

// ---------------- convert x fp32 -> bf16 ----------------
__global__ __launch_bounds__(256) void convert_x_kernel(
    const float* __restrict__ x, ushort_t* __restrict__ x_bf)
{
    int i = (blockIdx.x * 256 + threadIdx.x) * 8;
    float4 a = *reinterpret_cast<const float4*>(x + i);
    float4 b = *reinterpret_cast<const float4*>(x + i + 4);
    bf16x8 o;
    o[0] = (short)f2b(a.x); o[1] = (short)f2b(a.y);
    o[2] = (short)f2b(a.z); o[3] = (short)f2b(a.w);
    o[4] = (short)f2b(b.x); o[5] = (short)f2b(b.y);
    o[6] = (short)f2b(b.z); o[7] = (short)f2b(b.w);
    *reinterpret_cast<bf16x8*>(x_bf + i) = o;
}

// ---------------- gather expert rows from bf16 copy ----------------
__global__ __launch_bounds__(256) void gather_x_kernel(
    const ushort_t* __restrict__ x_bf, const int* __restrict__ slot_token,
    const int* __restrict__ counts_cap, ushort_t* __restrict__ xg)
{
    int row = blockIdx.x;            // [0, ECAP)
    int e = row / CAP;
    int pos = row - e * CAP;
    int tok = (pos < counts_cap[e]) ? slot_token[row] : 0;
    int c = threadIdx.x * 4;
    ushort4 v = *reinterpret_cast<const ushort4*>(x_bf + (size_t)tok * DIM + c);
    *reinterpret_cast<ushort4*>(xg + (size_t)row * DIM + c) = v;
}

// ---------------- transpose+convert weights: fp32 [K][N] -> bf16 [N][K] ----------------
__global__ __launch_bounds__(256) void transpose_w_kernel(
    const float* __restrict__ w1, const float* __restrict__ w2,
    const float* __restrict__ sw1, const float* __restrict__ sw2,
    ushort_t* __restrict__ w1t, ushort_t* __restrict__ w2t,
    ushort_t* __restrict__ sw1t, ushort_t* __restrict__ sw2t)
{
    __shared__ float tileT[64][65];   // [n][k]
    int bx = blockIdx.x;
    const float* src; ushort_t* dst; int K, N, kt, nt;
    if (bx < 2048) {                      // w1: per-expert [1024][512]
        int e = bx >> 7, r = bx & 127;
        K = 1024; N = 512; kt = r >> 3; nt = r & 7;
        src = w1 + (size_t)e * K * N; dst = w1t + (size_t)e * K * N;
    } else if (bx < 4096) {               // w2: per-expert [512][1024]
        int b2 = bx - 2048, e = b2 >> 7, r = b2 & 127;
        K = 512; N = 1024; kt = r >> 4; nt = r & 15;
        src = w2 + (size_t)e * K * N; dst = w2t + (size_t)e * K * N;
    } else if (bx < 4224) {               // sw1 [1024][512]
        int r = bx - 4096;
        K = 1024; N = 512; kt = r >> 3; nt = r & 7;
        src = sw1; dst = sw1t;
    } else {                              // sw2 [512][1024]
        int r = bx - 4224;
        K = 512; N = 1024; kt = r >> 4; nt = r & 15;
        src = sw2; dst = sw2t;
    }
    int t = threadIdx.x;
    int tr = t >> 4;
    int tc = (t & 15) * 4;
#pragma unroll
    for (int i = 0; i < 4; ++i) {
        int k = kt * 64 + i * 16 + tr;
        float4 v = *reinterpret_cast<const float4*>(src + (size_t)k * N + nt * 64 + tc);
        tileT[tc + 0][i * 16 + tr] = v.x;
        tileT[tc + 1][i * 16 + tr] = v.y;
        tileT[tc + 2][i * 16 + tr] = v.z;
        tileT[tc + 3][i * 16 + tr] = v.w;
    }
    __syncthreads();
    int wr = t >> 3;
    int wc = (t & 7) * 8;
#pragma unroll
    for (int i = 0; i < 2; ++i) {
        int n = wr + i * 32;
        bf16x8 o;
#pragma unroll
        for (int j = 0; j < 8; ++j) o[j] = (short)f2b(tileT[n][wc + j]);
        *reinterpret_cast<bf16x8*>(dst + (size_t)(nt * 64 + n) * K + kt * 64 + wc) = o;
    }
}

// ---------------- router: thread = (token, expert) ----------------
__global__ __launch_bounds__(256) void router_kernel(
    const float* __restrict__ x, const float* __restrict__ rw,
    const float* __restrict__ sgw,
    float* __restrict__ scores,
    int* __restrict__ topk_idx,
    float* __restrict__ topk_val,
    float* __restrict__ g_shared)
{
    int t = threadIdx.x;
    int e = t & 15;
    int token = blockIdx.x * 16 + (t >> 4);
    const float* xr = x + (size_t)token * DIM;

    float acc = 0.f;
#pragma unroll 4
    for (int d0 = 0; d0 < DIM; d0 += 4) {
        float4 xv = *reinterpret_cast<const float4*>(xr + d0);
        const float* rwd = rw + (size_t)d0 * NEXP + e;
        acc += xv.x * rwd[0];
        acc += xv.y * rwd[NEXP];
        acc += xv.z * rwd[2 * NEXP];
        acc += xv.w * rwd[3 * NEXP];
    }
    float accg = 0.f;
#pragma unroll 4
    for (int i = 0; i < DIM / 16; ++i) {
        int d = e + i * 16;
        accg += xr[d] * sgw[d];
    }
#pragma unroll
    for (int msk = 1; msk < 16; msk <<= 1)
        accg += __shfl_xor(accg, msk, 16);

    float mx = acc;
#pragma unroll
    for (int msk = 1; msk < 16; msk <<= 1)
        mx = fmaxf(mx, __shfl_xor(mx, msk, 16));
    float p = expf(acc - mx);
    float s = p;
#pragma unroll
    for (int msk = 1; msk < 16; msk <<= 1)
        s += __shfl_xor(s, msk, 16);
    p /= s;
    scores[(size_t)token * NEXP + e] = p;

    float v = p; int idx = e;
#pragma unroll
    for (int msk = 1; msk < 16; msk <<= 1) {
        float vo = __shfl_xor(v, msk, 16);
        int io = __shfl_xor(idx, msk, 16);
        if (vo > v || (vo == v && io < idx)) { v = vo; idx = io; }
    }
    int i0 = idx; float v0 = v;
    v = (e == i0) ? -1.f : p; idx = e;
#pragma unroll
    for (int msk = 1; msk < 16; msk <<= 1) {
        float vo = __shfl_xor(v, msk, 16);
        int io = __shfl_xor(idx, msk, 16);
        if (vo > v || (vo == v && io < idx)) { v = vo; idx = io; }
    }
    if (e == 0) {
        topk_idx[2 * token] = i0; topk_idx[2 * token + 1] = idx;
        topk_val[2 * token] = v0; topk_val[2 * token + 1] = v;
        g_shared[token] = 1.f / (1.f + expf(-accg));
    }
}

// ---------------- per-chunk expert histogram ----------------
__global__ __launch_bounds__(256) void hist_kernel(
    const int* __restrict__ topk_idx, int* __restrict__ chunk_hist)
{
    __shared__ int h[NEXP];
    int tid = threadIdx.x;
    if (tid < NEXP) h[tid] = 0;
    __syncthreads();
    int r = blockIdx.x * 256 + tid;
    atomicAdd(&h[topk_idx[r]], 1);
    __syncthreads();
    if (tid < NEXP) chunk_hist[blockIdx.x * NEXP + tid] = h[tid];
}

// ---------------- scan chunk histograms ----------------
__global__ __launch_bounds__(64) void scan_kernel(
    const int* __restrict__ chunk_hist, int* __restrict__ chunk_off,
    int* __restrict__ counts_cap, float* __restrict__ out_tail)
{
    int e = threadIdx.x;
    if (e >= NEXP) return;
    int run = 0;
    for (int b = 0; b < NCHUNK; ++b) {
        chunk_off[b * NEXP + e] = run;
        run += chunk_hist[b * NEXP + e];
    }
    counts_cap[e] = run < CAP ? run : CAP;
    out_tail[NEXP + e] = (float)((double)run / 16384.0);
}

// ---------------- deterministic slot assignment ----------------
__global__ __launch_bounds__(256) void assign_kernel(
    const int* __restrict__ topk_idx, const float* __restrict__ topk_val,
    const int* __restrict__ chunk_off,
    int* __restrict__ route_slot, int* __restrict__ slot_token)
{
    __shared__ int wave_cnt[4][NEXP];
    int tid = threadIdx.x;
    int lane = tid & 63;
    int w = tid >> 6;
    int r = blockIdx.x * 256 + tid;
    int e = topk_idx[r];
    float gate = topk_val[r];
    int rank_w = 0;
#pragma unroll
    for (int e16 = 0; e16 < NEXP; ++e16) {
        unsigned long long bal = __ballot(e == e16);
        if (e == e16) rank_w = __popcll(bal & ((1ull << lane) - 1ull));
        if (lane == 0) wave_cnt[w][e16] = __popcll(bal);
    }
    __syncthreads();
    int rank = rank_w;
#pragma unroll
    for (int w2 = 0; w2 < 3; ++w2)
        if (w2 < w) rank += wave_cnt[w2][e];
    int pos = chunk_off[blockIdx.x * NEXP + e] + rank;
    int slot = -1;
    if (pos < CAP && gate != 0.f) {
        slot = e * CAP + pos;
        slot_token[slot] = r >> 1;
    }
    route_slot[r] = slot;
}

// ---------------- importance reduction ----------------
__global__ __launch_bounds__(256) void importance_kernel(
    const float* __restrict__ scores, float* __restrict__ out_tail)
{
    __shared__ float red[256];
    int e = blockIdx.x;
    float s = 0.f;
    for (int t = threadIdx.x; t < N_TOK; t += 256) s += scores[t * NEXP + e];
    red[threadIdx.x] = s;
    __syncthreads();
    for (int st = 128; st > 0; st >>= 1) {
        if (threadIdx.x < st) red[threadIdx.x] += red[threadIdx.x + st];
        __syncthreads();
    }
    if (threadIdx.x == 0) out_tail[e] = red[0] / (float)N_TOK;
}

// ================= MFMA grouped GEMM 1: h = gelu(Xg @ W1) =================
// 128x128 tile, 4 waves, BK=32, 2-buffer, T1+T2. Dense A (xg / x_bf).
#define G_MB (NEXP * 10 + N_TOK / 128)      /* 224 */
#define G1_NWG (G_MB * (FDIM / 128))        /* 896 */
__global__ __launch_bounds__(256) void gemm1_mfma(
    const ushort_t* __restrict__ xg,        // [ECAP][DIM] bf16 (expert rows)
    const ushort_t* __restrict__ x_bf,      // [N_TOK][DIM] bf16 (shared rows)
    const ushort_t* __restrict__ w1t,       // [16][FDIM][DIM] bf16 n-major
    const ushort_t* __restrict__ sw1t,      // [FDIM][DIM]
    const int* __restrict__ counts_cap,
    ushort_t* __restrict__ h_buf)           // [TOTROW][FDIM] bf16
{
    __shared__ ushort_t As[2][128 * 32];    // 8KB per buffer
    __shared__ ushort_t Bs[2][128 * 32];

    int flat = blockIdx.x;
    int wg = (flat & 7) * (G1_NWG / 8) + (flat >> 3);   // T1 (896 % 8 == 0)
    int by = wg & 3;
    int bxg = wg >> 2;

    int g, rb;
    if (bxg < NEXP * 10) { g = bxg / 10; rb = bxg % 10; }
    else { g = NEXP; rb = bxg - NEXP * 10; }
    int Mg = (g < NEXP) ? counts_cap[g] : N_TOK;
    int m0 = rb * 128;
    if (m0 >= Mg) return;
    const ushort_t* Arows = (g < NEXP) ? (xg + (size_t)g * CAP * DIM) : x_bf;
    const ushort_t* Bt = (g < NEXP) ? (w1t + (size_t)g * DIM * FDIM) : sw1t;
    int n0 = by * 128;
    int t = threadIdx.x;

    const ushort_t* asrc[2];
    const ushort_t* bsrc[2];
#pragma unroll
    for (int i = 0; i < 2; ++i) {
        int s = t + i * 256;
        int lr = ((s >> 3) << 1) | ((s >> 2) & 1);
        int qq = (s & 3) ^ ((s >> 3) & 3);
        asrc[i] = Arows + (size_t)(m0 + lr) * DIM + qq * 8;
        bsrc[i] = Bt + (size_t)(n0 + lr) * DIM + qq * 8;
    }

    int lane = t & 63;
    int w = t >> 6;
    int wm = (w & 1) * 64, wn = (w >> 1) * 64;
    int l15 = lane & 15, q = lane >> 4;

    int aoff[4], boff[4];
#pragma unroll
    for (int m = 0; m < 4; ++m) aoff[m] = swz_addr16(wm + m * 16 + l15, q) << 3;
#pragma unroll
    for (int n = 0; n < 4; ++n) boff[n] = swz_addr16(wn + n * 16 + l15, q) << 3;

    f32x4 acc[4][4];
#pragma unroll
    for (int m = 0; m < 4; ++m)
#pragma unroll
        for (int n = 0; n < 4; ++n) acc[m][n] = (f32x4){0.f, 0.f, 0.f, 0.f};

    auto STAGE = [&](int buf, int koff) {
        gload16(asrc[0] + koff, &As[buf][t * 8]);
        gload16(asrc[1] + koff, &As[buf][t * 8 + 2048]);
        gload16(bsrc[0] + koff, &Bs[buf][t * 8]);
        gload16(bsrc[1] + koff, &Bs[buf][t * 8 + 2048]);
    };

    const int NSTEP = DIM / 32;   // 32
    STAGE(0, 0);
    __syncthreads();

    int cur = 0;
    for (int kt = 0; kt < NSTEP; ++kt) {
        if (kt + 1 < NSTEP) STAGE(cur ^ 1, (kt + 1) * 32);
        const ushort_t* asb = &As[cur][0];
        const ushort_t* bsb = &Bs[cur][0];
        bf16x8 af[4], bfr[4];
#pragma unroll
        for (int m = 0; m < 4; ++m)
            af[m] = *reinterpret_cast<const bf16x8*>(asb + aoff[m]);
#pragma unroll
        for (int n = 0; n < 4; ++n)
            bfr[n] = *reinterpret_cast<const bf16x8*>(bsb + boff[n]);
#pragma unroll
        for (int m = 0; m < 4; ++m)
#pragma unroll
            for (int n = 0; n < 4; ++n)
                acc[m][n] = __builtin_amdgcn_mfma_f32_16x16x32_bf16(
                    af[m], bfr[n], acc[m][n], 0, 0, 0);
        __syncthreads();
        cur ^= 1;
    }

    size_t obase = ((g < NEXP) ? (size_t)g * CAP : (size_t)ECAP) + m0;
#pragma unroll
    for (int m = 0; m < 4; ++m) {
#pragma unroll
        for (int r = 0; r < 4; ++r) {
            int grow = wm + m * 16 + q * 4 + r;
            ushort_t* orow = h_buf + (obase + grow) * FDIM + n0 + wn + l15;
#pragma unroll
            for (int n = 0; n < 4; ++n)
                orow[n * 16] = f2b(gelu_fast(acc[m][n][r]));
        }
    }
}

// ================= MFMA grouped GEMM 2: out = H @ W2 =================
#define G2_NWG (G_MB * (DIM / 128))         /* 1792 */
__global__ __launch_bounds__(256) void gemm2_mfma(
    const ushort_t* __restrict__ h_buf,     // [TOTROW][FDIM] bf16
    const ushort_t* __restrict__ w2t,       // [16][DIM][FDIM] bf16 n-major
    const ushort_t* __restrict__ sw2t,      // [DIM][FDIM]
    const int* __restrict__ counts_cap,
    const float* __restrict__ g_shared,
    ushort_t* __restrict__ out_buf,         // [ECAP][DIM] bf16
    float* __restrict__ y)                  // [N_TOK][DIM]
{
    __shared__ ushort_t As[2][128 * 32];
    __shared__ ushort_t Bs[2][128 * 32];

    int flat = blockIdx.x;
    int wg = (flat & 7) * (G2_NWG / 8) + (flat >> 3);
    int by = wg & 7;
    int bxg = wg >> 3;

    int g, rb;
    if (bxg < NEXP * 10) { g = bxg / 10; rb = bxg % 10; }
    else { g = NEXP; rb = bxg - NEXP * 10; }
    int Mg = (g < NEXP) ? counts_cap[g] : N_TOK;
    int m0 = rb * 128;
    if (m0 >= Mg) return;
    size_t abase = ((g < NEXP) ? (size_t)g * CAP : (size_t)ECAP) + m0;
    const ushort_t* Bt = (g < NEXP) ? (w2t + (size_t)g * FDIM * DIM) : sw2t;
    int n0 = by * 128;
    int t = threadIdx.x;

    const ushort_t* asrc[2];
    const ushort_t* bsrc[2];
#pragma unroll
    for (int i = 0; i < 2; ++i) {
        int s = t + i * 256;
        int lr = ((s >> 3) << 1) | ((s >> 2) & 1);
        int qq = (s & 3) ^ ((s >> 3) & 3);
        asrc[i] = h_buf + (abase + lr) * FDIM + qq * 8;
        bsrc[i] = Bt + (size_t)(n0 + lr) * FDIM + qq * 8;
    }

    int lane = t & 63;
    int w = t >> 6;
    int wm = (w & 1) * 64, wn = (w >> 1) * 64;
    int l15 = lane & 15, q = lane >> 4;

    int aoff[4], boff[4];
#pragma unroll
    for (int m = 0; m < 4; ++m) aoff[m] = swz_addr16(wm + m * 16 + l15, q) << 3;
#pragma unroll
    for (int n = 0; n < 4; ++n) boff[n] = swz_addr16(wn + n * 16 + l15, q) << 3;

    f32x4 acc[4][4];
#pragma unroll
    for (int m = 0; m < 4; ++m)
#pragma unroll
        for (int n = 0; n < 4; ++n) acc[m][n] = (f32x4){0.f, 0.f, 0.f, 0.f};

    auto STAGE = [&](int buf, int koff) {
        gload16(asrc[0] + koff, &As[buf][t * 8]);
        gload16(asrc[1] + koff, &As[buf][t * 8 + 2048]);
        gload16(bsrc[0] + koff, &Bs[buf][t * 8]);
        gload16(bsrc[1] + koff, &Bs[buf][t * 8 + 2048]);
    };

    const int NSTEP = FDIM / 32;  // 16
    STAGE(0, 0);
    __syncthreads();

    int cur = 0;
    for (int kt = 0; kt < NSTEP; ++kt) {
        if (kt + 1 < NSTEP) STAGE(cur ^ 1, (kt + 1) * 32);
        const ushort_t* asb = &As[cur][0];
        const ushort_t* bsb = &Bs[cur][0];
        bf16x8 af[4], bfr[4];
#pragma unroll
        for (int m = 0; m < 4; ++m)
            af[m] = *reinterpret_cast<const bf16x8*>(asb + aoff[m]);
#pragma unroll
        for (int n = 0; n < 4; ++n)
            bfr[n] = *reinterpret_cast<const bf16x8*>(bsb + boff[n]);
#pragma unroll
        for (int m = 0; m < 4; ++m)
#pragma unroll
            for (int n = 0; n < 4; ++n)
                acc[m][n] = __builtin_amdgcn_mfma_f32_16x16x32_bf16(
                    af[m], bfr[n], acc[m][n], 0, 0, 0);
        __syncthreads();
        cur ^= 1;
    }

    if (g < NEXP) {
#pragma unroll
        for (int m = 0; m < 4; ++m) {
#pragma unroll
            for (int r = 0; r < 4; ++r) {
                int grow = wm + m * 16 + q * 4 + r;
                ushort_t* orow = out_buf + (abase + grow) * DIM + n0 + wn + l15;
#pragma unroll
                for (int n = 0; n < 4; ++n)
                    orow[n * 16] = f2b(acc[m][n][r]);
            }
        }
    } else {
#pragma unroll
        for (int m = 0; m < 4; ++m) {
#pragma unroll
            for (int r = 0; r < 4; ++r) {
                int tok = m0 + wm + m * 16 + q * 4 + r;
                float gs = g_shared[tok];
                float* orow = y + (size_t)tok * DIM + n0 + wn + l15;
#pragma unroll
                for (int n = 0; n < 4; ++n)
                    orow[n * 16] = gs * acc[m][n][r];
            }
        }
    }
}

// ---------------- combine: y += sum(gate * expert_out) ----------------
__global__ __launch_bounds__(256) void combine_kernel(
    const ushort_t* __restrict__ out_buf,
    const int* __restrict__ route_slot, const float* __restrict__ topk_val,
    float* __restrict__ y)
{
    int token = blockIdx.x;
    int c = threadIdx.x * 4;
    float* yp = y + (size_t)token * DIM + c;
    float4 acc = *reinterpret_cast<float4*>(yp);
#pragma unroll
    for (int k = 0; k < 2; ++k) {
        int s = route_slot[2 * token + k];
        if (s >= 0) {
            float gate = topk_val[2 * token + k];
            ushort4 rv = *reinterpret_cast<const ushort4*>(out_buf + (size_t)s * DIM + c);
            acc.x += gate * bf2f(rv.x); acc.y += gate * bf2f(rv.y);
            acc.z += gate * bf2f(rv.z); acc.w += gate * bf2f(rv.w);
        }
    }
    *reinterpret_cast<float4*>(yp) = acc;
}

extern "C" void kernel_launch(void* const* d_in, const int* in_sizes, int n_in,
                              void* d_out, int out_size, void* d_ws, size_t ws_size,
                              hipStream_t stream) {
    const float* x   = (const float*)d_in[0];
    const float* rw  = (const float*)d_in[1];
    const float* sgw = (const float*)d_in[2];
    const float* w1  = (const float*)d_in[3];
    const float* w2  = (const float*)d_in[4];
    const float* sw1 = (const float*)d_in[5];
    const float* sw2 = (const float*)d_in[6];
    float* y = (float*)d_out;
    float* out_tail = y + (size_t)N_TOK * DIM;

    size_t off = 0;
    char* wsb = (char*)d_ws;
    auto alloc = [&](size_t bytes) -> void* {
        void* p = wsb + off;
        off += (bytes + 255) & ~(size_t)255;
        return p;
    };
    float*    scores     = (float*)alloc((size_t)N_TOK * NEXP * 4);
    int*      topk_idx   = (int*)alloc((size_t)NROUTE * 4);
    float*    topk_val   = (float*)alloc((size_t)NROUTE * 4);
    float*    g_shared   = (float*)alloc((size_t)N_TOK * 4);
    int*      chunk_hist = (int*)alloc((size_t)NCHUNK * NEXP * 4);
    int*      chunk_off  = (int*)alloc((size_t)NCHUNK * NEXP * 4);
    int*      counts_cap = (int*)alloc((size_t)NEXP * 4);
    int*      route_slot = (int*)alloc((size_t)NROUTE * 4);
    int*      slot_token = (int*)alloc((size_t)ECAP * 4);
    // xg [ECAP][DIM] aliased with out_buf [ECAP][DIM]: xg dead after gemm1.
    char*     xg_union   = (char*)alloc((size_t)ECAP * DIM * 2);
    ushort_t* xg         = (ushort_t*)xg_union;
    ushort_t* out_buf    = (ushort_t*)xg_union;
    ushort_t* x_bf       = (ushort_t*)alloc((size_t)N_TOK * DIM * 2);
    ushort_t* w1t        = (ushort_t*)alloc((size_t)NEXP * DIM * FDIM * 2);
    ushort_t* w2t        = (ushort_t*)alloc((size_t)NEXP * DIM * FDIM * 2);
    ushort_t* sw1t       = (ushort_t*)alloc((size_t)DIM * FDIM * 2);
    ushort_t* sw2t       = (ushort_t*)alloc((size_t)DIM * FDIM * 2);
    ushort_t* h_buf      = (ushort_t*)alloc((size_t)TOTROW * FDIM * 2);
    (void)ws_size; (void)in_sizes; (void)n_in; (void)out_size;

    transpose_w_kernel<<<4352, 256, 0, stream>>>(w1, w2, sw1, sw2, w1t, w2t, sw1t, sw2t);
    router_kernel<<<N_TOK / 16, 256, 0, stream>>>(x, rw, sgw, scores, topk_idx, topk_val, g_shared);
    hist_kernel<<<NCHUNK, 256, 0, stream>>>(topk_idx, chunk_hist);
    scan_kernel<<<1, 64, 0, stream>>>(chunk_hist, chunk_off, counts_cap, out_tail);
    assign_kernel<<<NCHUNK, 256, 0, stream>>>(topk_idx, topk_val, chunk_off, route_slot, slot_token);
    importance_kernel<<<NEXP, 256, 0, stream>>>(scores, out_tail);
    convert_x_kernel<<<N_TOK * DIM / 2048, 256, 0, stream>>>(x, x_bf);
    gather_x_kernel<<<ECAP, 256, 0, stream>>>(x_bf, slot_token, counts_cap, xg);

    gemm1_mfma<<<G1_NWG, 256, 0, stream>>>(xg, x_bf, w1t, sw1t, counts_cap, h_buf);
    gemm2_mfma<<<G2_NWG, 256, 0, stream>>>(h_buf, w2t, sw2t, counts_cap, g_shared, out_buf, y);

    combine_kernel<<<N_TOK, 256, 0, stream>>>(out_buf, route_slot, topk_val, y);
}

// Round 9
// 214.009 us; speedup vs baseline: 1.0894x; 1.0894x over previous
//
#include <hip/hip_runtime.h>
#include <hip/hip_bf16.h>
#include <math.h>

#define N_TOK 8192
#define DIM 1024
#define NEXP 16
#define CAP 1280
#define FDIM 512
#define NROUTE (N_TOK * 2)
#define NCHUNK 64
#define ECAP (NEXP * CAP)        /* 20480 */
#define TOTROW (ECAP + N_TOK)    /* 28672 */

typedef __hip_bfloat16 bf16;
typedef unsigned short ushort_t;
typedef __attribute__((ext_vector_type(8))) short bf16x8;
typedef __attribute__((ext_vector_type(4))) float f32x4;

// tanh-approx gelu via sigmoid; |err| vs erf-gelu ~1e-3 << tolerance.
__device__ __forceinline__ float gelu_fast(float x) {
    float u = 1.5957691216057308f * (x + 0.044715f * x * x * x);
    return x / (1.f + __expf(-u));
}

__device__ __forceinline__ float bf2f(unsigned short u) {
    union { float f; unsigned int i; } v; v.i = ((unsigned int)u) << 16; return v.f;
}

__device__ __forceinline__ unsigned short f2b(float f) {
    union { __hip_bfloat16 h; unsigned short u; } v;
    v.h = __float2bfloat16(f);
    return v.u;
}

__device__ __forceinline__ void gload16(const void* g, void* l) {
    __builtin_amdgcn_global_load_lds(
        (const __attribute__((address_space(1))) unsigned int*)g,
        (__attribute__((address_space(3))) unsigned int*)l,
        16, 0, 0);
}

// T2 both-sides swizzle (verified: SQ_LDS_BANK_CONFLICT -> 0, rounds 5-8)
__device__ __forceinline__ int swz_addr16(int r, int q) {
    return ((r >> 1) << 3) + ((r & 1) << 2) + (q ^ ((r >> 1) & 3));
}

// ---------------- convert x fp32 -> bf16 ----------------
__global__ __launch_bounds__(256) void convert_x_kernel(
    const float* __restrict__ x, ushort_t* __restrict__ x_bf)
{
    int i = (blockIdx.x * 256 + threadIdx.x) * 8;
    float4 a = *reinterpret_cast<const float4*>(x + i);
    float4 b = *reinterpret_cast<const float4*>(x + i + 4);
    bf16x8 o;
    o[0] = (short)f2b(a.x); o[1] = (short)f2b(a.y);
    o[2] = (short)f2b(a.z); o[3] = (short)f2b(a.w);
    o[4] = (short)f2b(b.x); o[5] = (short)f2b(b.y);
    o[6] = (short)f2b(b.z); o[7] = (short)f2b(b.w);
    *reinterpret_cast<bf16x8*>(x_bf + i) = o;
}

// ---------------- gather expert rows from bf16 copy ----------------
__global__ __launch_bounds__(256) void gather_x_kernel(
    const ushort_t* __restrict__ x_bf, const int* __restrict__ slot_token,
    const int* __restrict__ counts_cap, ushort_t* __restrict__ xg)
{
    int row = blockIdx.x;            // [0, ECAP)
    int e = row / CAP;
    int pos = row - e * CAP;
    int tok = (pos < counts_cap[e]) ? slot_token[row] : 0;
    int c = threadIdx.x * 4;
    ushort4 v = *reinterpret_cast<const ushort4*>(x_bf + (size_t)tok * DIM + c);
    *reinterpret_cast<ushort4*>(xg + (size_t)row * DIM + c) = v;
}

// ---------------- transpose+convert weights: fp32 [K][N] -> bf16 [N][K] ----------------
__global__ __launch_bounds__(256) void transpose_w_kernel(
    const float* __restrict__ w1, const float* __restrict__ w2,
    const float* __restrict__ sw1, const float* __restrict__ sw2,
    ushort_t* __restrict__ w1t, ushort_t* __restrict__ w2t,
    ushort_t* __restrict__ sw1t, ushort_t* __restrict__ sw2t)
{
    __shared__ float tileT[64][65];   // [n][k]
    int bx = blockIdx.x;
    const float* src; ushort_t* dst; int K, N, kt, nt;
    if (bx < 2048) {                      // w1: per-expert [1024][512]
        int e = bx >> 7, r = bx & 127;
        K = 1024; N = 512; kt = r >> 3; nt = r & 7;
        src = w1 + (size_t)e * K * N; dst = w1t + (size_t)e * K * N;
    } else if (bx < 4096) {               // w2: per-expert [512][1024]
        int b2 = bx - 2048, e = b2 >> 7, r = b2 & 127;
        K = 512; N = 1024; kt = r >> 4; nt = r & 15;
        src = w2 + (size_t)e * K * N; dst = w2t + (size_t)e * K * N;
    } else if (bx < 4224) {               // sw1 [1024][512]
        int r = bx - 4096;
        K = 1024; N = 512; kt = r >> 3; nt = r & 7;
        src = sw1; dst = sw1t;
    } else {                              // sw2 [512][1024]
        int r = bx - 4224;
        K = 512; N = 1024; kt = r >> 4; nt = r & 15;
        src = sw2; dst = sw2t;
    }
    int t = threadIdx.x;
    int tr = t >> 4;
    int tc = (t & 15) * 4;
#pragma unroll
    for (int i = 0; i < 4; ++i) {
        int k = kt * 64 + i * 16 + tr;
        float4 v = *reinterpret_cast<const float4*>(src + (size_t)k * N + nt * 64 + tc);
        tileT[tc + 0][i * 16 + tr] = v.x;
        tileT[tc + 1][i * 16 + tr] = v.y;
        tileT[tc + 2][i * 16 + tr] = v.z;
        tileT[tc + 3][i * 16 + tr] = v.w;
    }
    __syncthreads();
    int wr = t >> 3;
    int wc = (t & 7) * 8;
#pragma unroll
    for (int i = 0; i < 2; ++i) {
        int n = wr + i * 32;
        bf16x8 o;
#pragma unroll
        for (int j = 0; j < 8; ++j) o[j] = (short)f2b(tileT[n][wc + j]);
        *reinterpret_cast<bf16x8*>(dst + (size_t)(nt * 64 + n) * K + kt * 64 + wc) = o;
    }
}

// ---------------- router: thread = (token, expert) ----------------
__global__ __launch_bounds__(256) void router_kernel(
    const float* __restrict__ x, const float* __restrict__ rw,
    const float* __restrict__ sgw,
    float* __restrict__ scores,
    int* __restrict__ topk_idx,
    float* __restrict__ topk_val,
    float* __restrict__ g_shared)
{
    int t = threadIdx.x;
    int e = t & 15;
    int token = blockIdx.x * 16 + (t >> 4);
    const float* xr = x + (size_t)token * DIM;

    float acc = 0.f;
#pragma unroll 4
    for (int d0 = 0; d0 < DIM; d0 += 4) {
        float4 xv = *reinterpret_cast<const float4*>(xr + d0);
        const float* rwd = rw + (size_t)d0 * NEXP + e;
        acc += xv.x * rwd[0];
        acc += xv.y * rwd[NEXP];
        acc += xv.z * rwd[2 * NEXP];
        acc += xv.w * rwd[3 * NEXP];
    }
    float accg = 0.f;
#pragma unroll 4
    for (int i = 0; i < DIM / 16; ++i) {
        int d = e + i * 16;
        accg += xr[d] * sgw[d];
    }
#pragma unroll
    for (int msk = 1; msk < 16; msk <<= 1)
        accg += __shfl_xor(accg, msk, 16);

    float mx = acc;
#pragma unroll
    for (int msk = 1; msk < 16; msk <<= 1)
        mx = fmaxf(mx, __shfl_xor(mx, msk, 16));
    float p = expf(acc - mx);
    float s = p;
#pragma unroll
    for (int msk = 1; msk < 16; msk <<= 1)
        s += __shfl_xor(s, msk, 16);
    p /= s;
    scores[(size_t)token * NEXP + e] = p;

    float v = p; int idx = e;
#pragma unroll
    for (int msk = 1; msk < 16; msk <<= 1) {
        float vo = __shfl_xor(v, msk, 16);
        int io = __shfl_xor(idx, msk, 16);
        if (vo > v || (vo == v && io < idx)) { v = vo; idx = io; }
    }
    int i0 = idx; float v0 = v;
    v = (e == i0) ? -1.f : p; idx = e;
#pragma unroll
    for (int msk = 1; msk < 16; msk <<= 1) {
        float vo = __shfl_xor(v, msk, 16);
        int io = __shfl_xor(idx, msk, 16);
        if (vo > v || (vo == v && io < idx)) { v = vo; idx = io; }
    }
    if (e == 0) {
        topk_idx[2 * token] = i0; topk_idx[2 * token + 1] = idx;
        topk_val[2 * token] = v0; topk_val[2 * token + 1] = v;
        g_shared[token] = 1.f / (1.f + expf(-accg));
    }
}

// ---------------- per-chunk expert histogram ----------------
__global__ __launch_bounds__(256) void hist_kernel(
    const int* __restrict__ topk_idx, int* __restrict__ chunk_hist)
{
    __shared__ int h[NEXP];
    int tid = threadIdx.x;
    if (tid < NEXP) h[tid] = 0;
    __syncthreads();
    int r = blockIdx.x * 256 + tid;
    atomicAdd(&h[topk_idx[r]], 1);
    __syncthreads();
    if (tid < NEXP) chunk_hist[blockIdx.x * NEXP + tid] = h[tid];
}

// ---------------- scan chunk histograms ----------------
__global__ __launch_bounds__(64) void scan_kernel(
    const int* __restrict__ chunk_hist, int* __restrict__ chunk_off,
    int* __restrict__ counts_cap, float* __restrict__ out_tail)
{
    int e = threadIdx.x;
    if (e >= NEXP) return;
    int run = 0;
    for (int b = 0; b < NCHUNK; ++b) {
        chunk_off[b * NEXP + e] = run;
        run += chunk_hist[b * NEXP + e];
    }
    counts_cap[e] = run < CAP ? run : CAP;
    out_tail[NEXP + e] = (float)((double)run / 16384.0);
}

// ---------------- deterministic slot assignment ----------------
__global__ __launch_bounds__(256) void assign_kernel(
    const int* __restrict__ topk_idx, const float* __restrict__ topk_val,
    const int* __restrict__ chunk_off,
    int* __restrict__ route_slot, int* __restrict__ slot_token)
{
    __shared__ int wave_cnt[4][NEXP];
    int tid = threadIdx.x;
    int lane = tid & 63;
    int w = tid >> 6;
    int r = blockIdx.x * 256 + tid;
    int e = topk_idx[r];
    float gate = topk_val[r];
    int rank_w = 0;
#pragma unroll
    for (int e16 = 0; e16 < NEXP; ++e16) {
        unsigned long long bal = __ballot(e == e16);
        if (e == e16) rank_w = __popcll(bal & ((1ull << lane) - 1ull));
        if (lane == 0) wave_cnt[w][e16] = __popcll(bal);
    }
    __syncthreads();
    int rank = rank_w;
#pragma unroll
    for (int w2 = 0; w2 < 3; ++w2)
        if (w2 < w) rank += wave_cnt[w2][e];
    int pos = chunk_off[blockIdx.x * NEXP + e] + rank;
    int slot = -1;
    if (pos < CAP && gate != 0.f) {
        slot = e * CAP + pos;
        slot_token[slot] = r >> 1;
    }
    route_slot[r] = slot;
}

// ---------------- importance reduction ----------------
__global__ __launch_bounds__(256) void importance_kernel(
    const float* __restrict__ scores, float* __restrict__ out_tail)
{
    __shared__ float red[256];
    int e = blockIdx.x;
    float s = 0.f;
    for (int t = threadIdx.x; t < N_TOK; t += 256) s += scores[t * NEXP + e];
    red[threadIdx.x] = s;
    __syncthreads();
    for (int st = 128; st > 0; st >>= 1) {
        if (threadIdx.x < st) red[threadIdx.x] += red[threadIdx.x + st];
        __syncthreads();
    }
    if (threadIdx.x == 0) out_tail[e] = red[0] / (float)N_TOK;
}

// ================= MFMA grouped GEMM 1: h = gelu(Xg @ W1) =================
// 256x128 tile, 8 waves, BK=32. 3-buffer LDS, counted vmcnt(3) (loads issued
// 2 K-steps ahead, never drained to 0 mid-loop), setprio, T1+T2.
#define G1_GX (NEXP * 5 + N_TOK / 256)      /* 112 */
#define G1_NWG (G1_GX * (FDIM / 128))       /* 448 */
__global__ __launch_bounds__(512) void gemm1_mfma(
    const ushort_t* __restrict__ xg,        // [ECAP][DIM] bf16 (expert rows)
    const ushort_t* __restrict__ x_bf,      // [N_TOK][DIM] bf16 (shared rows)
    const ushort_t* __restrict__ w1t,       // [16][FDIM][DIM] bf16 n-major
    const ushort_t* __restrict__ sw1t,      // [FDIM][DIM]
    const int* __restrict__ counts_cap,
    ushort_t* __restrict__ h_buf)           // [TOTROW][FDIM] bf16
{
    __shared__ ushort_t As[3][256 * 32];    // 16KB x3
    __shared__ ushort_t Bs[3][128 * 32];    // 8KB x3

    int flat = blockIdx.x;
    int wg = (flat & 7) * (G1_NWG / 8) + (flat >> 3);   // T1 (448 % 8 == 0)
    int by = wg & 3;
    int bxg = wg >> 2;

    int g, rb;
    if (bxg < NEXP * 5) { g = bxg / 5; rb = bxg % 5; }
    else { g = NEXP; rb = bxg - NEXP * 5; }
    int Mg = (g < NEXP) ? counts_cap[g] : N_TOK;
    int m0 = rb * 256;
    if (m0 >= Mg) return;
    const ushort_t* Arows = (g < NEXP) ? (xg + ((size_t)g * CAP + m0) * DIM)
                                       : (x_bf + (size_t)m0 * DIM);
    const ushort_t* Bt = (g < NEXP) ? (w1t + (size_t)g * DIM * FDIM) : sw1t;
    int n0 = by * 128;
    int t = threadIdx.x;

    const ushort_t* asrc[2];
    const ushort_t* bsrc;
#pragma unroll
    for (int i = 0; i < 2; ++i) {
        int s = t + i * 512;
        int lr = ((s >> 3) << 1) | ((s >> 2) & 1);
        int qq = (s & 3) ^ ((s >> 3) & 3);
        asrc[i] = Arows + (size_t)lr * DIM + qq * 8;
    }
    {
        int s = t;
        int lr = ((s >> 3) << 1) | ((s >> 2) & 1);
        int qq = (s & 3) ^ ((s >> 3) & 3);
        bsrc = Bt + (size_t)(n0 + lr) * DIM + qq * 8;
    }

    int lane = t & 63;
    int w = t >> 6;
    int wm = (w & 3) * 64, wn = (w >> 2) * 64;
    int l15 = lane & 15, q = lane >> 4;

    int aoff[4], boff[4];
#pragma unroll
    for (int m = 0; m < 4; ++m) aoff[m] = swz_addr16(wm + m * 16 + l15, q) << 3;
#pragma unroll
    for (int n = 0; n < 4; ++n) boff[n] = swz_addr16(wn + n * 16 + l15, q) << 3;

    f32x4 acc[4][4];
#pragma unroll
    for (int m = 0; m < 4; ++m)
#pragma unroll
        for (int n = 0; n < 4; ++n) acc[m][n] = (f32x4){0.f, 0.f, 0.f, 0.f};

    auto STAGE = [&](int buf, int koff) {
        gload16(asrc[0] + koff, &As[buf][t * 8]);
        gload16(asrc[1] + koff, &As[buf][t * 8 + 4096]);
        gload16(bsrc + koff, &Bs[buf][t * 8]);
    };

    const int NSTEP = DIM / 32;   // 32
    STAGE(0, 0);
    STAGE(1, 32);
    asm volatile("s_waitcnt vmcnt(3)" ::: "memory");
    __builtin_amdgcn_s_barrier();
    asm volatile("" ::: "memory");

    int cur = 0, b2 = 2;
    for (int kt = 0; kt < NSTEP; ++kt) {
        if (kt + 2 < NSTEP) STAGE(b2, (kt + 2) * 32);
        const ushort_t* asb = &As[cur][0];
        const ushort_t* bsb = &Bs[cur][0];
        bf16x8 af[4], bfr[4];
#pragma unroll
        for (int m = 0; m < 4; ++m)
            af[m] = *reinterpret_cast<const bf16x8*>(asb + aoff[m]);
#pragma unroll
        for (int n = 0; n < 4; ++n)
            bfr[n] = *reinterpret_cast<const bf16x8*>(bsb + boff[n]);
        __builtin_amdgcn_s_setprio(1);
#pragma unroll
        for (int m = 0; m < 4; ++m)
#pragma unroll
            for (int n = 0; n < 4; ++n)
                acc[m][n] = __builtin_amdgcn_mfma_f32_16x16x32_bf16(
                    af[m], bfr[n], acc[m][n], 0, 0, 0);
        __builtin_amdgcn_s_setprio(0);
        if (kt + 1 < NSTEP) {
            if (kt + 2 < NSTEP) asm volatile("s_waitcnt vmcnt(3)" ::: "memory");
            else                asm volatile("s_waitcnt vmcnt(0)" ::: "memory");
            __builtin_amdgcn_s_barrier();
            asm volatile("" ::: "memory");
        }
        cur = (cur == 2) ? 0 : cur + 1;
        b2  = (b2 == 2) ? 0 : b2 + 1;
    }

    size_t obase = ((g < NEXP) ? (size_t)g * CAP : (size_t)ECAP) + m0;
#pragma unroll
    for (int m = 0; m < 4; ++m) {
#pragma unroll
        for (int r = 0; r < 4; ++r) {
            int grow = wm + m * 16 + q * 4 + r;
            ushort_t* orow = h_buf + (obase + grow) * FDIM + n0 + wn + l15;
#pragma unroll
            for (int n = 0; n < 4; ++n)
                orow[n * 16] = f2b(gelu_fast(acc[m][n][r]));
        }
    }
}

// ================= MFMA grouped GEMM 2: out = H @ W2 =================
#define G2_NWG (G1_GX * (DIM / 128))        /* 896 */
__global__ __launch_bounds__(512) void gemm2_mfma(
    const ushort_t* __restrict__ h_buf,     // [TOTROW][FDIM] bf16
    const ushort_t* __restrict__ w2t,       // [16][DIM][FDIM] bf16 n-major
    const ushort_t* __restrict__ sw2t,      // [DIM][FDIM]
    const int* __restrict__ counts_cap,
    const float* __restrict__ g_shared,
    ushort_t* __restrict__ out_buf,         // [ECAP][DIM] bf16
    float* __restrict__ y)                  // [N_TOK][DIM]
{
    __shared__ ushort_t As[3][256 * 32];
    __shared__ ushort_t Bs[3][128 * 32];

    int flat = blockIdx.x;
    int wg = (flat & 7) * (G2_NWG / 8) + (flat >> 3);
    int by = wg & 7;
    int bxg = wg >> 3;

    int g, rb;
    if (bxg < NEXP * 5) { g = bxg / 5; rb = bxg % 5; }
    else { g = NEXP; rb = bxg - NEXP * 5; }
    int Mg = (g < NEXP) ? counts_cap[g] : N_TOK;
    int m0 = rb * 256;
    if (m0 >= Mg) return;
    size_t abase = ((g < NEXP) ? (size_t)g * CAP : (size_t)ECAP) + m0;
    const ushort_t* Bt = (g < NEXP) ? (w2t + (size_t)g * FDIM * DIM) : sw2t;
    int n0 = by * 128;
    int t = threadIdx.x;

    const ushort_t* asrc[2];
    const ushort_t* bsrc;
#pragma unroll
    for (int i = 0; i < 2; ++i) {
        int s = t + i * 512;
        int lr = ((s >> 3) << 1) | ((s >> 2) & 1);
        int qq = (s & 3) ^ ((s >> 3) & 3);
        asrc[i] = h_buf + (abase + lr) * FDIM + qq * 8;
    }
    {
        int s = t;
        int lr = ((s >> 3) << 1) | ((s >> 2) & 1);
        int qq = (s & 3) ^ ((s >> 3) & 3);
        bsrc = Bt + (size_t)(n0 + lr) * FDIM + qq * 8;
    }

    int lane = t & 63;
    int w = t >> 6;
    int wm = (w & 3) * 64, wn = (w >> 2) * 64;
    int l15 = lane & 15, q = lane >> 4;

    int aoff[4], boff[4];
#pragma unroll
    for (int m = 0; m < 4; ++m) aoff[m] = swz_addr16(wm + m * 16 + l15, q) << 3;
#pragma unroll
    for (int n = 0; n < 4; ++n) boff[n] = swz_addr16(wn + n * 16 + l15, q) << 3;

    f32x4 acc[4][4];
#pragma unroll
    for (int m = 0; m < 4; ++m)
#pragma unroll
        for (int n = 0; n < 4; ++n) acc[m][n] = (f32x4){0.f, 0.f, 0.f, 0.f};

    auto STAGE = [&](int buf, int koff) {
        gload16(asrc[0] + koff, &As[buf][t * 8]);
        gload16(asrc[1] + koff, &As[buf][t * 8 + 4096]);
        gload16(bsrc + koff, &Bs[buf][t * 8]);
    };

    const int NSTEP = FDIM / 32;  // 16
    STAGE(0, 0);
    STAGE(1, 32);
    asm volatile("s_waitcnt vmcnt(3)" ::: "memory");
    __builtin_amdgcn_s_barrier();
    asm volatile("" ::: "memory");

    int cur = 0, b2 = 2;
    for (int kt = 0; kt < NSTEP; ++kt) {
        if (kt + 2 < NSTEP) STAGE(b2, (kt + 2) * 32);
        const ushort_t* asb = &As[cur][0];
        const ushort_t* bsb = &Bs[cur][0];
        bf16x8 af[4], bfr[4];
#pragma unroll
        for (int m = 0; m < 4; ++m)
            af[m] = *reinterpret_cast<const bf16x8*>(asb + aoff[m]);
#pragma unroll
        for (int n = 0; n < 4; ++n)
            bfr[n] = *reinterpret_cast<const bf16x8*>(bsb + boff[n]);
        __builtin_amdgcn_s_setprio(1);
#pragma unroll
        for (int m = 0; m < 4; ++m)
#pragma unroll
            for (int n = 0; n < 4; ++n)
                acc[m][n] = __builtin_amdgcn_mfma_f32_16x16x32_bf16(
                    af[m], bfr[n], acc[m][n], 0, 0, 0);
        __builtin_amdgcn_s_setprio(0);
        if (kt + 1 < NSTEP) {
            if (kt + 2 < NSTEP) asm volatile("s_waitcnt vmcnt(3)" ::: "memory");
            else                asm volatile("s_waitcnt vmcnt(0)" ::: "memory");
            __builtin_amdgcn_s_barrier();
            asm volatile("" ::: "memory");
        }
        cur = (cur == 2) ? 0 : cur + 1;
        b2  = (b2 == 2) ? 0 : b2 + 1;
    }

    if (g < NEXP) {
#pragma unroll
        for (int m = 0; m < 4; ++m) {
#pragma unroll
            for (int r = 0; r < 4; ++r) {
                int grow = wm + m * 16 + q * 4 + r;
                ushort_t* orow = out_buf + (abase + grow) * DIM + n0 + wn + l15;
#pragma unroll
                for (int n = 0; n < 4; ++n)
                    orow[n * 16] = f2b(acc[m][n][r]);
            }
        }
    } else {
#pragma unroll
        for (int m = 0; m < 4; ++m) {
#pragma unroll
            for (int r = 0; r < 4; ++r) {
                int tok = m0 + wm + m * 16 + q * 4 + r;
                float gs = g_shared[tok];
                float* orow = y + (size_t)tok * DIM + n0 + wn + l15;
#pragma unroll
                for (int n = 0; n < 4; ++n)
                    orow[n * 16] = gs * acc[m][n][r];
            }
        }
    }
}

// ---------------- combine: y += sum(gate * expert_out) ----------------
__global__ __launch_bounds__(256) void combine_kernel(
    const ushort_t* __restrict__ out_buf,
    const int* __restrict__ route_slot, const float* __restrict__ topk_val,
    float* __restrict__ y)
{
    int token = blockIdx.x;
    int c = threadIdx.x * 4;
    float* yp = y + (size_t)token * DIM + c;
    float4 acc = *reinterpret_cast<float4*>(yp);
#pragma unroll
    for (int k = 0; k < 2; ++k) {
        int s = route_slot[2 * token + k];
        if (s >= 0) {
            float gate = topk_val[2 * token + k];
            ushort4 rv = *reinterpret_cast<const ushort4*>(out_buf + (size_t)s * DIM + c);
            acc.x += gate * bf2f(rv.x); acc.y += gate * bf2f(rv.y);
            acc.z += gate * bf2f(rv.z); acc.w += gate * bf2f(rv.w);
        }
    }
    *reinterpret_cast<float4*>(yp) = acc;
}

extern "C" void kernel_launch(void* const* d_in, const int* in_sizes, int n_in,
                              void* d_out, int out_size, void* d_ws, size_t ws_size,
                              hipStream_t stream) {
    const float* x   = (const float*)d_in[0];
    const float* rw  = (const float*)d_in[1];
    const float* sgw = (const float*)d_in[2];
    const float* w1  = (const float*)d_in[3];
    const float* w2  = (const float*)d_in[4];
    const float* sw1 = (const float*)d_in[5];
    const float* sw2 = (const float*)d_in[6];
    float* y = (float*)d_out;
    float* out_tail = y + (size_t)N_TOK * DIM;

    size_t off = 0;
    char* wsb = (char*)d_ws;
    auto alloc = [&](size_t bytes) -> void* {
        void* p = wsb + off;
        off += (bytes + 255) & ~(size_t)255;
        return p;
    };
    float*    scores     = (float*)alloc((size_t)N_TOK * NEXP * 4);
    int*      topk_idx   = (int*)alloc((size_t)NROUTE * 4);
    float*    topk_val   = (float*)alloc((size_t)NROUTE * 4);
    float*    g_shared   = (float*)alloc((size_t)N_TOK * 4);
    int*      chunk_hist = (int*)alloc((size_t)NCHUNK * NEXP * 4);
    int*      chunk_off  = (int*)alloc((size_t)NCHUNK * NEXP * 4);
    int*      counts_cap = (int*)alloc((size_t)NEXP * 4);
    int*      route_slot = (int*)alloc((size_t)NROUTE * 4);
    int*      slot_token = (int*)alloc((size_t)ECAP * 4);
    // xg [ECAP][DIM] aliased with out_buf [ECAP][DIM]: xg dead after gemm1.
    char*     xg_union   = (char*)alloc((size_t)ECAP * DIM * 2);
    ushort_t* xg         = (ushort_t*)xg_union;
    ushort_t* out_buf    = (ushort_t*)xg_union;
    ushort_t* x_bf       = (ushort_t*)alloc((size_t)N_TOK * DIM * 2);
    ushort_t* w1t        = (ushort_t*)alloc((size_t)NEXP * DIM * FDIM * 2);
    ushort_t* w2t        = (ushort_t*)alloc((size_t)NEXP * DIM * FDIM * 2);
    ushort_t* sw1t       = (ushort_t*)alloc((size_t)DIM * FDIM * 2);
    ushort_t* sw2t       = (ushort_t*)alloc((size_t)DIM * FDIM * 2);
    ushort_t* h_buf      = (ushort_t*)alloc((size_t)TOTROW * FDIM * 2);
    (void)ws_size; (void)in_sizes; (void)n_in; (void)out_size;

    transpose_w_kernel<<<4352, 256, 0, stream>>>(w1, w2, sw1, sw2, w1t, w2t, sw1t, sw2t);
    router_kernel<<<N_TOK / 16, 256, 0, stream>>>(x, rw, sgw, scores, topk_idx, topk_val, g_shared);
    hist_kernel<<<NCHUNK, 256, 0, stream>>>(topk_idx, chunk_hist);
    scan_kernel<<<1, 64, 0, stream>>>(chunk_hist, chunk_off, counts_cap, out_tail);
    assign_kernel<<<NCHUNK, 256, 0, stream>>>(topk_idx, topk_val, chunk_off, route_slot, slot_token);
    importance_kernel<<<NEXP, 256, 0, stream>>>(scores, out_tail);
    convert_x_kernel<<<N_TOK * DIM / 2048, 256, 0, stream>>>(x, x_bf);
    gather_x_kernel<<<ECAP, 256, 0, stream>>>(x_bf, slot_token, counts_cap, xg);

    gemm1_mfma<<<G1_NWG, 512, 0, stream>>>(xg, x_bf, w1t, sw1t, counts_cap, h_buf);
    gemm2_mfma<<<G2_NWG, 512, 0, stream>>>(h_buf, w2t, sw2t, counts_cap, g_shared, out_buf, y);

    combine_kernel<<<N_TOK, 256, 0, stream>>>(out_buf, route_slot, topk_val, y);
}

// Round 10
// 192.919 us; speedup vs baseline: 1.2085x; 1.1093x over previous
//
#include <hip/hip_runtime.h>
#include <hip/hip_bf16.h>
#include <math.h>

#define N_TOK 8192
#define DIM 1024
#define NEXP 16
#define CAP 1280
#define FDIM 512
#define NROUTE (N_TOK * 2)
#define NCHUNK 64
#define ECAP (NEXP * CAP)        /* 20480 */
#define TOTROW (ECAP + N_TOK)    /* 28672 */

typedef __hip_bfloat16 bf16;
typedef unsigned short ushort_t;
typedef __attribute__((ext_vector_type(8))) short bf16x8;
typedef __attribute__((ext_vector_type(4))) float f32x4;

// tanh-approx gelu via sigmoid; |err| vs erf-gelu ~1e-3 << tolerance.
__device__ __forceinline__ float gelu_fast(float x) {
    float u = 1.5957691216057308f * (x + 0.044715f * x * x * x);
    return x / (1.f + __expf(-u));
}

__device__ __forceinline__ float bf2f(unsigned short u) {
    union { float f; unsigned int i; } v; v.i = ((unsigned int)u) << 16; return v.f;
}

__device__ __forceinline__ unsigned short f2b(float f) {
    union { __hip_bfloat16 h; unsigned short u; } v;
    v.h = __float2bfloat16(f);
    return v.u;
}

__device__ __forceinline__ void gload16(const void* g, void* l) {
    __builtin_amdgcn_global_load_lds(
        (const __attribute__((address_space(1))) unsigned int*)g,
        (__attribute__((address_space(3))) unsigned int*)l,
        16, 0, 0);
}

// T2 both-sides swizzle (verified: SQ_LDS_BANK_CONFLICT -> 0, rounds 5-9)
__device__ __forceinline__ int swz_addr16(int r, int q) {
    return ((r >> 1) << 3) + ((r & 1) << 2) + (q ^ ((r >> 1) & 3));
}

// ---------------- gather expert rows from bf16 copy ----------------
__global__ __launch_bounds__(256) void gather_x_kernel(
    const ushort_t* __restrict__ x_bf, const int* __restrict__ slot_token,
    const int* __restrict__ counts_cap, ushort_t* __restrict__ xg)
{
    int row = blockIdx.x;            // [0, ECAP)
    int e = row / CAP;
    int pos = row - e * CAP;
    int tok = (pos < counts_cap[e]) ? slot_token[row] : 0;
    int c = threadIdx.x * 4;
    ushort4 v = *reinterpret_cast<const ushort4*>(x_bf + (size_t)tok * DIM + c);
    *reinterpret_cast<ushort4*>(xg + (size_t)row * DIM + c) = v;
}

// ---------------- transpose+convert weights: fp32 [K][N] -> bf16 [N][K] ----------------
__global__ __launch_bounds__(256) void transpose_w_kernel(
    const float* __restrict__ w1, const float* __restrict__ w2,
    const float* __restrict__ sw1, const float* __restrict__ sw2,
    ushort_t* __restrict__ w1t, ushort_t* __restrict__ w2t,
    ushort_t* __restrict__ sw1t, ushort_t* __restrict__ sw2t)
{
    __shared__ float tileT[64][65];   // [n][k]
    int bx = blockIdx.x;
    const float* src; ushort_t* dst; int K, N, kt, nt;
    if (bx < 2048) {                      // w1: per-expert [1024][512]
        int e = bx >> 7, r = bx & 127;
        K = 1024; N = 512; kt = r >> 3; nt = r & 7;
        src = w1 + (size_t)e * K * N; dst = w1t + (size_t)e * K * N;
    } else if (bx < 4096) {               // w2: per-expert [512][1024]
        int b2 = bx - 2048, e = b2 >> 7, r = b2 & 127;
        K = 512; N = 1024; kt = r >> 4; nt = r & 15;
        src = w2 + (size_t)e * K * N; dst = w2t + (size_t)e * K * N;
    } else if (bx < 4224) {               // sw1 [1024][512]
        int r = bx - 4096;
        K = 1024; N = 512; kt = r >> 3; nt = r & 7;
        src = sw1; dst = sw1t;
    } else {                              // sw2 [512][1024]
        int r = bx - 4224;
        K = 512; N = 1024; kt = r >> 4; nt = r & 15;
        src = sw2; dst = sw2t;
    }
    int t = threadIdx.x;
    int tr = t >> 4;
    int tc = (t & 15) * 4;
#pragma unroll
    for (int i = 0; i < 4; ++i) {
        int k = kt * 64 + i * 16 + tr;
        float4 v = *reinterpret_cast<const float4*>(src + (size_t)k * N + nt * 64 + tc);
        tileT[tc + 0][i * 16 + tr] = v.x;
        tileT[tc + 1][i * 16 + tr] = v.y;
        tileT[tc + 2][i * 16 + tr] = v.z;
        tileT[tc + 3][i * 16 + tr] = v.w;
    }
    __syncthreads();
    int wr = t >> 3;
    int wc = (t & 7) * 8;
#pragma unroll
    for (int i = 0; i < 2; ++i) {
        int n = wr + i * 32;
        bf16x8 o;
#pragma unroll
        for (int j = 0; j < 8; ++j) o[j] = (short)f2b(tileT[n][wc + j]);
        *reinterpret_cast<bf16x8*>(dst + (size_t)(nt * 64 + n) * K + kt * 64 + wc) = o;
    }
}

// ---------------- router: thread = (token, expert); also emits x_bf ----------------
__global__ __launch_bounds__(256) void router_kernel(
    const float* __restrict__ x, const float* __restrict__ rw,
    const float* __restrict__ sgw,
    float* __restrict__ scores,
    int* __restrict__ topk_idx,
    float* __restrict__ topk_val,
    float* __restrict__ g_shared,
    ushort_t* __restrict__ x_bf)
{
    int t = threadIdx.x;
    int e = t & 15;
    int token = blockIdx.x * 16 + (t >> 4);
    const float* xr = x + (size_t)token * DIM;

    float acc = 0.f;
#pragma unroll 4
    for (int d0 = 0; d0 < DIM; d0 += 4) {
        float4 xv = *reinterpret_cast<const float4*>(xr + d0);
        const float* rwd = rw + (size_t)d0 * NEXP + e;
        acc += xv.x * rwd[0];
        acc += xv.y * rwd[NEXP];
        acc += xv.z * rwd[2 * NEXP];
        acc += xv.w * rwd[3 * NEXP];
    }
    // bf16 conversion: lane e writes cols [e*64, (e+1)*64) (L1-hot re-read)
    {
        const float* xs = xr + e * 64;
        ushort_t* xb = x_bf + (size_t)token * DIM + e * 64;
#pragma unroll
        for (int i = 0; i < 8; ++i) {
            float4 a = *reinterpret_cast<const float4*>(xs + i * 8);
            float4 b = *reinterpret_cast<const float4*>(xs + i * 8 + 4);
            bf16x8 o;
            o[0] = (short)f2b(a.x); o[1] = (short)f2b(a.y);
            o[2] = (short)f2b(a.z); o[3] = (short)f2b(a.w);
            o[4] = (short)f2b(b.x); o[5] = (short)f2b(b.y);
            o[6] = (short)f2b(b.z); o[7] = (short)f2b(b.w);
            *reinterpret_cast<bf16x8*>(xb + i * 8) = o;
        }
    }
    float accg = 0.f;
#pragma unroll 4
    for (int i = 0; i < DIM / 16; ++i) {
        int d = e + i * 16;
        accg += xr[d] * sgw[d];
    }
#pragma unroll
    for (int msk = 1; msk < 16; msk <<= 1)
        accg += __shfl_xor(accg, msk, 16);

    float mx = acc;
#pragma unroll
    for (int msk = 1; msk < 16; msk <<= 1)
        mx = fmaxf(mx, __shfl_xor(mx, msk, 16));
    float p = expf(acc - mx);
    float s = p;
#pragma unroll
    for (int msk = 1; msk < 16; msk <<= 1)
        s += __shfl_xor(s, msk, 16);
    p /= s;
    scores[(size_t)token * NEXP + e] = p;

    float v = p; int idx = e;
#pragma unroll
    for (int msk = 1; msk < 16; msk <<= 1) {
        float vo = __shfl_xor(v, msk, 16);
        int io = __shfl_xor(idx, msk, 16);
        if (vo > v || (vo == v && io < idx)) { v = vo; idx = io; }
    }
    int i0 = idx; float v0 = v;
    v = (e == i0) ? -1.f : p; idx = e;
#pragma unroll
    for (int msk = 1; msk < 16; msk <<= 1) {
        float vo = __shfl_xor(v, msk, 16);
        int io = __shfl_xor(idx, msk, 16);
        if (vo > v || (vo == v && io < idx)) { v = vo; idx = io; }
    }
    if (e == 0) {
        topk_idx[2 * token] = i0; topk_idx[2 * token + 1] = idx;
        topk_val[2 * token] = v0; topk_val[2 * token + 1] = v;
        g_shared[token] = 1.f / (1.f + expf(-accg));
    }
}

// ---------------- per-chunk expert histogram ----------------
__global__ __launch_bounds__(256) void hist_kernel(
    const int* __restrict__ topk_idx, int* __restrict__ chunk_hist)
{
    __shared__ int h[NEXP];
    int tid = threadIdx.x;
    if (tid < NEXP) h[tid] = 0;
    __syncthreads();
    int r = blockIdx.x * 256 + tid;
    atomicAdd(&h[topk_idx[r]], 1);
    __syncthreads();
    if (tid < NEXP) chunk_hist[blockIdx.x * NEXP + tid] = h[tid];
}

// ---------------- scan chunk histograms ----------------
__global__ __launch_bounds__(64) void scan_kernel(
    const int* __restrict__ chunk_hist, int* __restrict__ chunk_off,
    int* __restrict__ counts_cap, float* __restrict__ out_tail)
{
    int e = threadIdx.x;
    if (e >= NEXP) return;
    int run = 0;
    for (int b = 0; b < NCHUNK; ++b) {
        chunk_off[b * NEXP + e] = run;
        run += chunk_hist[b * NEXP + e];
    }
    counts_cap[e] = run < CAP ? run : CAP;
    out_tail[NEXP + e] = (float)((double)run / 16384.0);
}

// ---------------- deterministic slot assignment ----------------
__global__ __launch_bounds__(256) void assign_kernel(
    const int* __restrict__ topk_idx, const float* __restrict__ topk_val,
    const int* __restrict__ chunk_off,
    int* __restrict__ route_slot, int* __restrict__ slot_token)
{
    __shared__ int wave_cnt[4][NEXP];
    int tid = threadIdx.x;
    int lane = tid & 63;
    int w = tid >> 6;
    int r = blockIdx.x * 256 + tid;
    int e = topk_idx[r];
    float gate = topk_val[r];
    int rank_w = 0;
#pragma unroll
    for (int e16 = 0; e16 < NEXP; ++e16) {
        unsigned long long bal = __ballot(e == e16);
        if (e == e16) rank_w = __popcll(bal & ((1ull << lane) - 1ull));
        if (lane == 0) wave_cnt[w][e16] = __popcll(bal);
    }
    __syncthreads();
    int rank = rank_w;
#pragma unroll
    for (int w2 = 0; w2 < 3; ++w2)
        if (w2 < w) rank += wave_cnt[w2][e];
    int pos = chunk_off[blockIdx.x * NEXP + e] + rank;
    int slot = -1;
    if (pos < CAP && gate != 0.f) {
        slot = e * CAP + pos;
        slot_token[slot] = r >> 1;
    }
    route_slot[r] = slot;
}

// ---------------- importance reduction ----------------
__global__ __launch_bounds__(256) void importance_kernel(
    const float* __restrict__ scores, float* __restrict__ out_tail)
{
    __shared__ float red[256];
    int e = blockIdx.x;
    float s = 0.f;
    for (int t = threadIdx.x; t < N_TOK; t += 256) s += scores[t * NEXP + e];
    red[threadIdx.x] = s;
    __syncthreads();
    for (int st = 128; st > 0; st >>= 1) {
        if (threadIdx.x < st) red[threadIdx.x] += red[threadIdx.x + st];
        __syncthreads();
    }
    if (threadIdx.x == 0) out_tail[e] = red[0] / (float)N_TOK;
}

// ================= MFMA grouped GEMM 1: h = gelu(Xg @ W1) =================
// 256x128 tile, 8 waves, BK=32, 3-buffer LDS, counted vmcnt(3), setprio, T1+T2.
#define G1_GX (NEXP * 5 + N_TOK / 256)      /* 112 */
#define G1_NWG (G1_GX * (FDIM / 128))       /* 448 */
__global__ __launch_bounds__(512) void gemm1_mfma(
    const ushort_t* __restrict__ xg,        // [ECAP][DIM] bf16 (expert rows)
    const ushort_t* __restrict__ x_bf,      // [N_TOK][DIM] bf16 (shared rows)
    const ushort_t* __restrict__ w1t,       // [16][FDIM][DIM] bf16 n-major
    const ushort_t* __restrict__ sw1t,      // [FDIM][DIM]
    const int* __restrict__ counts_cap,
    ushort_t* __restrict__ h_buf)           // [TOTROW][FDIM] bf16
{
    __shared__ ushort_t As[3][256 * 32];
    __shared__ ushort_t Bs[3][128 * 32];

    int flat = blockIdx.x;
    int wg = (flat & 7) * (G1_NWG / 8) + (flat >> 3);   // T1 (448 % 8 == 0)
    int by = wg & 3;
    int bxg = wg >> 2;

    int g, rb;
    if (bxg < NEXP * 5) { g = bxg / 5; rb = bxg % 5; }
    else { g = NEXP; rb = bxg - NEXP * 5; }
    int Mg = (g < NEXP) ? counts_cap[g] : N_TOK;
    int m0 = rb * 256;
    if (m0 >= Mg) return;
    const ushort_t* Arows = (g < NEXP) ? (xg + ((size_t)g * CAP + m0) * DIM)
                                       : (x_bf + (size_t)m0 * DIM);
    const ushort_t* Bt = (g < NEXP) ? (w1t + (size_t)g * DIM * FDIM) : sw1t;
    int n0 = by * 128;
    int t = threadIdx.x;

    const ushort_t* asrc[2];
    const ushort_t* bsrc;
#pragma unroll
    for (int i = 0; i < 2; ++i) {
        int s = t + i * 512;
        int lr = ((s >> 3) << 1) | ((s >> 2) & 1);
        int qq = (s & 3) ^ ((s >> 3) & 3);
        asrc[i] = Arows + (size_t)lr * DIM + qq * 8;
    }
    {
        int s = t;
        int lr = ((s >> 3) << 1) | ((s >> 2) & 1);
        int qq = (s & 3) ^ ((s >> 3) & 3);
        bsrc = Bt + (size_t)(n0 + lr) * DIM + qq * 8;
    }

    int lane = t & 63;
    int w = t >> 6;
    int wm = (w & 3) * 64, wn = (w >> 2) * 64;
    int l15 = lane & 15, q = lane >> 4;

    int aoff[4], boff[4];
#pragma unroll
    for (int m = 0; m < 4; ++m) aoff[m] = swz_addr16(wm + m * 16 + l15, q) << 3;
#pragma unroll
    for (int n = 0; n < 4; ++n) boff[n] = swz_addr16(wn + n * 16 + l15, q) << 3;

    f32x4 acc[4][4];
#pragma unroll
    for (int m = 0; m < 4; ++m)
#pragma unroll
        for (int n = 0; n < 4; ++n) acc[m][n] = (f32x4){0.f, 0.f, 0.f, 0.f};

    auto STAGE = [&](int buf, int koff) {
        gload16(asrc[0] + koff, &As[buf][t * 8]);
        gload16(asrc[1] + koff, &As[buf][t * 8 + 4096]);
        gload16(bsrc + koff, &Bs[buf][t * 8]);
    };

    const int NSTEP = DIM / 32;   // 32
    STAGE(0, 0);
    STAGE(1, 32);
    asm volatile("s_waitcnt vmcnt(3)" ::: "memory");
    __builtin_amdgcn_s_barrier();
    asm volatile("" ::: "memory");

    int cur = 0, b2 = 2;
    for (int kt = 0; kt < NSTEP; ++kt) {
        if (kt + 2 < NSTEP) STAGE(b2, (kt + 2) * 32);
        const ushort_t* asb = &As[cur][0];
        const ushort_t* bsb = &Bs[cur][0];
        bf16x8 af[4], bfr[4];
#pragma unroll
        for (int m = 0; m < 4; ++m)
            af[m] = *reinterpret_cast<const bf16x8*>(asb + aoff[m]);
#pragma unroll
        for (int n = 0; n < 4; ++n)
            bfr[n] = *reinterpret_cast<const bf16x8*>(bsb + boff[n]);
        __builtin_amdgcn_s_setprio(1);
#pragma unroll
        for (int m = 0; m < 4; ++m)
#pragma unroll
            for (int n = 0; n < 4; ++n)
                acc[m][n] = __builtin_amdgcn_mfma_f32_16x16x32_bf16(
                    af[m], bfr[n], acc[m][n], 0, 0, 0);
        __builtin_amdgcn_s_setprio(0);
        if (kt + 1 < NSTEP) {
            if (kt + 2 < NSTEP) asm volatile("s_waitcnt vmcnt(3)" ::: "memory");
            else                asm volatile("s_waitcnt vmcnt(0)" ::: "memory");
            __builtin_amdgcn_s_barrier();
            asm volatile("" ::: "memory");
        }
        cur = (cur == 2) ? 0 : cur + 1;
        b2  = (b2 == 2) ? 0 : b2 + 1;
    }

    size_t obase = ((g < NEXP) ? (size_t)g * CAP : (size_t)ECAP) + m0;
#pragma unroll
    for (int m = 0; m < 4; ++m) {
#pragma unroll
        for (int r = 0; r < 4; ++r) {
            int grow = wm + m * 16 + q * 4 + r;
            ushort_t* orow = h_buf + (obase + grow) * FDIM + n0 + wn + l15;
#pragma unroll
            for (int n = 0; n < 4; ++n)
                orow[n * 16] = f2b(gelu_fast(acc[m][n][r]));
        }
    }
}

// ================= MFMA grouped GEMM 2: out = H @ W2 =================
// 256x128 tile, 8 waves, BK=32, 2-buffer (48KB, occupancy), setprio, T1+T2.
// experts -> out_buf (bf16); shared -> sh_out = bf16(g_shared * val).
#define G2_NWG (G1_GX * (DIM / 128))        /* 896 */
__global__ __launch_bounds__(512) void gemm2_mfma(
    const ushort_t* __restrict__ h_buf,     // [TOTROW][FDIM] bf16
    const ushort_t* __restrict__ w2t,       // [16][DIM][FDIM] bf16 n-major
    const ushort_t* __restrict__ sw2t,      // [DIM][FDIM]
    const int* __restrict__ counts_cap,
    const float* __restrict__ g_shared,
    ushort_t* __restrict__ out_buf,         // [ECAP][DIM] bf16
    ushort_t* __restrict__ sh_out)          // [N_TOK][DIM] bf16 (x_bf reuse)
{
    __shared__ ushort_t As[2][256 * 32];
    __shared__ ushort_t Bs[2][128 * 32];

    int flat = blockIdx.x;
    int wg = (flat & 7) * (G2_NWG / 8) + (flat >> 3);
    int by = wg & 7;
    int bxg = wg >> 3;

    int g, rb;
    if (bxg < NEXP * 5) { g = bxg / 5; rb = bxg % 5; }
    else { g = NEXP; rb = bxg - NEXP * 5; }
    int Mg = (g < NEXP) ? counts_cap[g] : N_TOK;
    int m0 = rb * 256;
    if (m0 >= Mg) return;
    size_t abase = ((g < NEXP) ? (size_t)g * CAP : (size_t)ECAP) + m0;
    const ushort_t* Bt = (g < NEXP) ? (w2t + (size_t)g * FDIM * DIM) : sw2t;
    int n0 = by * 128;
    int t = threadIdx.x;

    const ushort_t* asrc[2];
    const ushort_t* bsrc;
#pragma unroll
    for (int i = 0; i < 2; ++i) {
        int s = t + i * 512;
        int lr = ((s >> 3) << 1) | ((s >> 2) & 1);
        int qq = (s & 3) ^ ((s >> 3) & 3);
        asrc[i] = h_buf + (abase + lr) * FDIM + qq * 8;
    }
    {
        int s = t;
        int lr = ((s >> 3) << 1) | ((s >> 2) & 1);
        int qq = (s & 3) ^ ((s >> 3) & 3);
        bsrc = Bt + (size_t)(n0 + lr) * FDIM + qq * 8;
    }

    int lane = t & 63;
    int w = t >> 6;
    int wm = (w & 3) * 64, wn = (w >> 2) * 64;
    int l15 = lane & 15, q = lane >> 4;

    int aoff[4], boff[4];
#pragma unroll
    for (int m = 0; m < 4; ++m) aoff[m] = swz_addr16(wm + m * 16 + l15, q) << 3;
#pragma unroll
    for (int n = 0; n < 4; ++n) boff[n] = swz_addr16(wn + n * 16 + l15, q) << 3;

    f32x4 acc[4][4];
#pragma unroll
    for (int m = 0; m < 4; ++m)
#pragma unroll
        for (int n = 0; n < 4; ++n) acc[m][n] = (f32x4){0.f, 0.f, 0.f, 0.f};

    auto STAGE = [&](int buf, int koff) {
        gload16(asrc[0] + koff, &As[buf][t * 8]);
        gload16(asrc[1] + koff, &As[buf][t * 8 + 4096]);
        gload16(bsrc + koff, &Bs[buf][t * 8]);
    };

    const int NSTEP = FDIM / 32;  // 16
    STAGE(0, 0);
    __syncthreads();

    int cur = 0;
    for (int kt = 0; kt < NSTEP; ++kt) {
        if (kt + 1 < NSTEP) STAGE(cur ^ 1, (kt + 1) * 32);
        const ushort_t* asb = &As[cur][0];
        const ushort_t* bsb = &Bs[cur][0];
        bf16x8 af[4], bfr[4];
#pragma unroll
        for (int m = 0; m < 4; ++m)
            af[m] = *reinterpret_cast<const bf16x8*>(asb + aoff[m]);
#pragma unroll
        for (int n = 0; n < 4; ++n)
            bfr[n] = *reinterpret_cast<const bf16x8*>(bsb + boff[n]);
        __builtin_amdgcn_s_setprio(1);
#pragma unroll
        for (int m = 0; m < 4; ++m)
#pragma unroll
            for (int n = 0; n < 4; ++n)
                acc[m][n] = __builtin_amdgcn_mfma_f32_16x16x32_bf16(
                    af[m], bfr[n], acc[m][n], 0, 0, 0);
        __builtin_amdgcn_s_setprio(0);
        __syncthreads();
        cur ^= 1;
    }

    if (g < NEXP) {
#pragma unroll
        for (int m = 0; m < 4; ++m) {
#pragma unroll
            for (int r = 0; r < 4; ++r) {
                int grow = wm + m * 16 + q * 4 + r;
                ushort_t* orow = out_buf + (abase + grow) * DIM + n0 + wn + l15;
#pragma unroll
                for (int n = 0; n < 4; ++n)
                    orow[n * 16] = f2b(acc[m][n][r]);
            }
        }
    } else {
#pragma unroll
        for (int m = 0; m < 4; ++m) {
#pragma unroll
            for (int r = 0; r < 4; ++r) {
                int tok = m0 + wm + m * 16 + q * 4 + r;
                float gs = g_shared[tok];
                ushort_t* orow = sh_out + (size_t)tok * DIM + n0 + wn + l15;
#pragma unroll
                for (int n = 0; n < 4; ++n)
                    orow[n * 16] = f2b(gs * acc[m][n][r]);
            }
        }
    }
}

// ---------------- combine: y = sh_out + sum(gate * expert_out), write-only ----------------
__global__ __launch_bounds__(256) void combine_kernel(
    const ushort_t* __restrict__ out_buf, const ushort_t* __restrict__ sh_out,
    const int* __restrict__ route_slot, const float* __restrict__ topk_val,
    float* __restrict__ y)
{
    int token = blockIdx.x;
    int c = threadIdx.x * 4;
    ushort4 sv = *reinterpret_cast<const ushort4*>(sh_out + (size_t)token * DIM + c);
    float y0 = bf2f(sv.x), y1 = bf2f(sv.y), y2 = bf2f(sv.z), y3 = bf2f(sv.w);
#pragma unroll
    for (int k = 0; k < 2; ++k) {
        int s = route_slot[2 * token + k];
        if (s >= 0) {
            float gate = topk_val[2 * token + k];
            ushort4 rv = *reinterpret_cast<const ushort4*>(out_buf + (size_t)s * DIM + c);
            y0 += gate * bf2f(rv.x); y1 += gate * bf2f(rv.y);
            y2 += gate * bf2f(rv.z); y3 += gate * bf2f(rv.w);
        }
    }
    float4 o; o.x = y0; o.y = y1; o.z = y2; o.w = y3;
    *reinterpret_cast<float4*>(y + (size_t)token * DIM + c) = o;
}

extern "C" void kernel_launch(void* const* d_in, const int* in_sizes, int n_in,
                              void* d_out, int out_size, void* d_ws, size_t ws_size,
                              hipStream_t stream) {
    const float* x   = (const float*)d_in[0];
    const float* rw  = (const float*)d_in[1];
    const float* sgw = (const float*)d_in[2];
    const float* w1  = (const float*)d_in[3];
    const float* w2  = (const float*)d_in[4];
    const float* sw1 = (const float*)d_in[5];
    const float* sw2 = (const float*)d_in[6];
    float* y = (float*)d_out;
    float* out_tail = y + (size_t)N_TOK * DIM;

    size_t off = 0;
    char* wsb = (char*)d_ws;
    auto alloc = [&](size_t bytes) -> void* {
        void* p = wsb + off;
        off += (bytes + 255) & ~(size_t)255;
        return p;
    };
    float*    scores     = (float*)alloc((size_t)N_TOK * NEXP * 4);
    int*      topk_idx   = (int*)alloc((size_t)NROUTE * 4);
    float*    topk_val   = (float*)alloc((size_t)NROUTE * 4);
    float*    g_shared   = (float*)alloc((size_t)N_TOK * 4);
    int*      chunk_hist = (int*)alloc((size_t)NCHUNK * NEXP * 4);
    int*      chunk_off  = (int*)alloc((size_t)NCHUNK * NEXP * 4);
    int*      counts_cap = (int*)alloc((size_t)NEXP * 4);
    int*      route_slot = (int*)alloc((size_t)NROUTE * 4);
    int*      slot_token = (int*)alloc((size_t)ECAP * 4);
    // xg [ECAP][DIM] aliased with out_buf: xg dead after gemm1.
    char*     xg_union   = (char*)alloc((size_t)ECAP * DIM * 2);
    ushort_t* xg         = (ushort_t*)xg_union;
    ushort_t* out_buf    = (ushort_t*)xg_union;
    // x_bf [N_TOK][DIM] reused as sh_out after gemm1 (x_bf dead post-gemm1).
    ushort_t* x_bf       = (ushort_t*)alloc((size_t)N_TOK * DIM * 2);
    ushort_t* sh_out     = x_bf;
    ushort_t* w1t        = (ushort_t*)alloc((size_t)NEXP * DIM * FDIM * 2);
    ushort_t* w2t        = (ushort_t*)alloc((size_t)NEXP * DIM * FDIM * 2);
    ushort_t* sw1t       = (ushort_t*)alloc((size_t)DIM * FDIM * 2);
    ushort_t* sw2t       = (ushort_t*)alloc((size_t)DIM * FDIM * 2);
    ushort_t* h_buf      = (ushort_t*)alloc((size_t)TOTROW * FDIM * 2);
    (void)ws_size; (void)in_sizes; (void)n_in; (void)out_size;

    transpose_w_kernel<<<4352, 256, 0, stream>>>(w1, w2, sw1, sw2, w1t, w2t, sw1t, sw2t);
    router_kernel<<<N_TOK / 16, 256, 0, stream>>>(x, rw, sgw, scores, topk_idx, topk_val, g_shared, x_bf);
    hist_kernel<<<NCHUNK, 256, 0, stream>>>(topk_idx, chunk_hist);
    scan_kernel<<<1, 64, 0, stream>>>(chunk_hist, chunk_off, counts_cap, out_tail);
    assign_kernel<<<NCHUNK, 256, 0, stream>>>(topk_idx, topk_val, chunk_off, route_slot, slot_token);
    importance_kernel<<<NEXP, 256, 0, stream>>>(scores, out_tail);
    gather_x_kernel<<<ECAP, 256, 0, stream>>>(x_bf, slot_token, counts_cap, xg);

    gemm1_mfma<<<G1_NWG, 512, 0, stream>>>(xg, x_bf, w1t, sw1t, counts_cap, h_buf);
    gemm2_mfma<<<G2_NWG, 512, 0, stream>>>(h_buf, w2t, sw2t, counts_cap, g_shared, out_buf, sh_out);

    combine_kernel<<<N_TOK, 256, 0, stream>>>(out_buf, sh_out, route_slot, topk_val, y);
}